// Round 6
// baseline (218.065 us; speedup 1.0000x reference)
//
#include <hip/hip_runtime.h>

// Problem constants (B=16, D=128, H=32, W=32, K=8192)
#define D 128
#define HW 1024
#define NROWS 16384
#define K 8192
#define NU 32   // 32-col units per block (1024-col k-split / 32)

// d_out layout (float offsets): z_q_st | indices | new_codebook | new_count | new_weight
#define OUT0 0
#define OUT1 2097152
#define OUT2 2113536
#define OUT3 3162112
#define OUT4 3170304

typedef __attribute__((ext_vector_type(8))) _Float16 half8;
typedef __attribute__((ext_vector_type(16))) float f32x16;
typedef unsigned short u16;
typedef unsigned long long u64;

// ---- async global->LDS, 16B per lane (dst = wave-uniform base + lane*16) ----
__device__ __forceinline__ void gld16(const u16* gsrc, u16* ldst) {
    __builtin_amdgcn_global_load_lds(
        (const __attribute__((address_space(1))) unsigned int*)gsrc,
        (__attribute__((address_space(3))) unsigned int*)ldst,
        16, 0, 0);
}

// ---- fused prep: blocks [0,512) codebook-split + cnorm + dw-zero;
//      blocks [512,1536) z-split + packed-init + counts-zero ----
// B layout: [unit g(256)][ Bh: [kk(16)][col(32)][j(8)] | Bl: same ] (16 KiB/unit)
// A layout: [band(n>>5)][ks(8)][lh(2)][row(32)][j(8)]
__global__ __launch_bounds__(256) void k_prep(const float* __restrict__ cb,
                                              const float* __restrict__ z_e,
                                              u16* __restrict__ Bg,
                                              float* __restrict__ cnorm,
                                              u16* __restrict__ Ah, u16* __restrict__ Al,
                                              u64* __restrict__ packed,
                                              float* __restrict__ counts,
                                              float* __restrict__ dw) {
    const int tid = threadIdx.x;
    if (blockIdx.x < 512) {
        int kk = tid & 15;
        int k = blockIdx.x * 16 + (tid >> 4);
        const float* src = cb + (size_t)k * D + kk * 8;
        half8 h, l;
        float s = 0.f;
#pragma unroll
        for (int j = 0; j < 8; ++j) {
            float v = src[j];
            s += v * v;
            _Float16 hv = (_Float16)v;              // RN f32->f16
            _Float16 lv = (_Float16)(v - (float)hv);
            h[j] = hv;
            l[j] = lv;
        }
        int g = k >> 5, col = k & 31;
        size_t offH = (size_t)g * 8192 + ((size_t)kk * 32 + col) * 8;
        *(half8*)((_Float16*)Bg + offH) = h;
        *(half8*)((_Float16*)Bg + offH + 4096) = l;
#pragma unroll
        for (int off = 8; off > 0; off >>= 1) s += __shfl_down(s, off);
        if (kk == 0) cnorm[k] = s;
        // zero dw: 131072 threads x 8 floats = K*D exactly
        float4 z4 = {0.f, 0.f, 0.f, 0.f};
        size_t zi = ((size_t)blockIdx.x * 256 + tid) * 8;
        *(float4*)(dw + zi) = z4;
        *(float4*)(dw + zi + 4) = z4;
    } else {
        int gid = (blockIdx.x - 512) * 256 + tid;   // NROWS*16 threads
        int n  = gid & (NROWS - 1);                 // lane-contiguous n -> coalesced
        int kk = gid >> 14;                         // 0..15
        int b = n >> 10, hw = n & 1023;
        const float* src = z_e + ((size_t)b * D + kk * 8) * HW + hw;
        half8 h, l;
#pragma unroll
        for (int j = 0; j < 8; ++j) {
            float v = src[(size_t)j * HW];
            _Float16 hv = (_Float16)v;
            _Float16 lv = (_Float16)(v - (float)hv);
            h[j] = hv;
            l[j] = lv;
        }
        int rg = n >> 7, band = (n >> 5) & 3, row = n & 31;
        size_t off = (((((size_t)rg * 4 + band) * 8 + (kk >> 1)) * 2 + (kk & 1)) * 32 + row) * 8;
        *(half8*)(Ah + off) = h;
        *(half8*)(Al + off) = l;
        if (kk == 0) {
            packed[n] = ~0ull;                      // +inf sentinel
            if (n < K) counts[n] = 0.f;
        }
    }
}

// ---- main: 3-pass fp16-split distance GEMM + fused argmin ----
// R6: R0-R5 all sat at ~37-42% MfmaUtil (= the m97-structure ceiling) with
// per-pass ds_reads placed just before their MFMAs -> one full LDS round-trip
// stall per pass per unit while the shallow MFMA pipe drains. Fix: hoist ALL
// 16 B-frag reads of the unit into a b[16] reg array BEFORE any MFMA (m201's
// load-whole-phase-then-burst pattern) -- bl arrives under the vmcnt/barrier
// shadow, bh arrives under pass-1's MFMA crunch. One latency exposure/unit.
// Geometry: 256-thr blocks (4 waves x one 32-row tile), 1024 blocks =
// 128 rg x 8 ks; ks = bid&7 pins each ksplit to one XCD (B slice 512 KB,
// L2-resident). launch_bounds(256,2): ~200 regs, 2 blocks/CU. Cheap fold
// (cmp + 2 cndmask). Counted vmcnt(5) prefetch across raw s_barrier.
__global__ __launch_bounds__(256, 2) void k_argmin_mfma(
        const u16* __restrict__ Ahg, const u16* __restrict__ Alg,
        const u16* __restrict__ Bg,
        const float* __restrict__ cnorm, u64* __restrict__ packed) {
    __shared__ u16 lds[2][8192];                // 2 x 16 KiB

    const int tid = threadIdx.x;
    const int ln  = tid & 63;
    const int l31 = ln & 31;
    const int lh  = ln >> 5;                    // k-half select within frag
    const int wy  = tid >> 6;                   // wave 0..3

    const int bid = blockIdx.x;                 // 1024 = 128 rg x 8 ks
    const int ks_ = bid & 7;                    // XCD (bid%8) owns one ksplit
    const int rg  = bid >> 3;

    const int k0 = ks_ * 1024;                  // k split
    const int g0 = k0 >> 5;                     // first 32-col B-unit
    const int band = rg * 4 + wy;               // global 32-row band 0..511

    // ---- A fragments -> registers (read once from global; 64 VGPRs) ----
    half8 Ah[8], Al[8];
#pragma unroll
    for (int ks = 0; ks < 8; ++ks) {
        size_t off = ((((size_t)band * 8 + ks) * 2 + lh) * 32 + l31) * 8;
        Ah[ks] = *(const half8*)((const _Float16*)Ahg + off);
        Al[ks] = *(const half8*)((const _Float16*)Alg + off);
    }

    // ---- prologue: stage unit 0 (16 KiB, 4 gld16/thread); full drain ----
    {
        const u16* src = Bg + (size_t)g0 * 8192;
#pragma unroll
        for (int r = 0; r < 4; ++r)
            gld16(src + ((size_t)r * 256 + tid) * 8, lds[0] + (r * 256 + tid) * 8);
    }
    asm volatile("s_waitcnt vmcnt(0)" ::: "memory");
    asm volatile("s_barrier" ::: "memory");

    float minv[16];
    int   mini[16];
#pragma unroll
    for (int r = 0; r < 16; ++r) { minv[r] = INFINITY; mini[r] = 0; }

#pragma unroll 1
    for (int u = 0; u < NU; ++u) {
        const u16* buf = lds[u & 1];
        const int c0 = k0 + u * 32 + l31;

        // cn use is at the fold; compiler auto-guards the reg dep w/ vmcnt
        float cn0 = cnorm[c0];

        if (u + 1 < NU) {
            const u16* src = Bg + (size_t)(g0 + u + 1) * 8192;
            u16* dst = lds[(u + 1) & 1];
#pragma unroll
            for (int r = 0; r < 4; ++r)
                gld16(src + ((size_t)r * 256 + tid) * 8, dst + (r * 256 + tid) * 8);
            // exactly this iter's 5 VMEM ops (cn + 4 gld) may stay in flight:
            // everything older (incl. this unit's stage) is retired.
            asm volatile("s_waitcnt vmcnt(5)" ::: "memory");
        } else {
            asm volatile("s_waitcnt vmcnt(0)" ::: "memory");
        }
        asm volatile("s_barrier" ::: "memory");

        const _Float16* bh = (const _Float16*)buf;
        const _Float16* bl = bh + 4096;

        // ---- hoist ALL 16 B-frag reads before any MFMA (the R6 change).
        // Read order matches consume order: bl (pass 1) first, bh after.
        half8 b[16];
#pragma unroll
        for (int ks = 0; ks < 8; ++ks)
            b[ks] = *(const half8*)(bl + ((ks * 2 + lh) * 32 + l31) * 8);
#pragma unroll
        for (int ks = 0; ks < 8; ++ks)
            b[8 + ks] = *(const half8*)(bh + ((ks * 2 + lh) * 32 + l31) * 8);

        f32x16 acc = {};
        __builtin_amdgcn_s_setprio(1);
        // pass 1: Ah x Bl
#pragma unroll
        for (int ks = 0; ks < 8; ++ks)
            acc = __builtin_amdgcn_mfma_f32_32x32x16_f16(Ah[ks], b[ks], acc, 0, 0, 0);
        // passes 2+3: Ah x Bh, Al x Bh (b-frag shared)
#pragma unroll
        for (int ks = 0; ks < 8; ++ks) {
            acc = __builtin_amdgcn_mfma_f32_32x32x16_f16(Ah[ks], b[8 + ks], acc, 0, 0, 0);
            acc = __builtin_amdgcn_mfma_f32_32x32x16_f16(Al[ks], b[8 + ks], acc, 0, 0, 0);
        }
        __builtin_amdgcn_s_setprio(0);

        // fold dist = cnorm - 2*dot into running argmin (cmp + 2 cndmask)
#pragma unroll
        for (int r = 0; r < 16; ++r) {
            float d0 = fmaf(-2.0f, acc[r], cn0);
            bool p = d0 < minv[r];
            minv[r] = p ? d0 : minv[r];
            mini[r] = p ? c0 : mini[r];
        }
        // all waves done reading buf before its sibling is overwritten next iter
        asm volatile("s_barrier" ::: "memory");
    }

    // ---- reduce across the 32 l31-lanes sharing each output row ----
#pragma unroll
    for (int r = 0; r < 16; ++r) {
        float v = minv[r];
        int ix = mini[r];
#pragma unroll
        for (int off = 1; off < 32; off <<= 1) {
            float v2 = __shfl_xor(v, off);
            int i2 = __shfl_xor(ix, off);
            if (v2 < v || (v2 == v && i2 < ix)) { v = v2; ix = i2; }
        }
        if (l31 == 0) {
            // C/D row map (m74/m101): row = (reg&3) + 8*(reg>>2) + 4*(lane>>5)
            int row = band * 32 + 4 * lh + (r & 3) + 8 * (r >> 2);
            unsigned int uenc = __float_as_uint(v);
            uenc = (uenc & 0x80000000u) ? ~uenc : (uenc | 0x80000000u);  // monotonic
            u64 pk = ((u64)uenc << 13) | (u64)(unsigned)ix;
            atomicMin(&packed[row], pk);
        }
    }
}

// ---- epilogue: indices, z_q_st, counts, dw ----
__global__ __launch_bounds__(256) void k_epilogue(const float* __restrict__ z_e,
                                                  const float* __restrict__ cb,
                                                  const u64* __restrict__ packed,
                                                  float* __restrict__ out0,
                                                  float* __restrict__ out1,
                                                  float* __restrict__ counts,
                                                  float* __restrict__ dw) {
    __shared__ int idxS[64];
    const int tid = threadIdx.x;
    const int n0 = blockIdx.x * 64;
    const int bb = n0 >> 10, p0 = n0 & 1023;

    if (tid < 64) {
        int ix = (int)(packed[n0 + tid] & 0x1FFFull);
        idxS[tid] = ix;
        out1[n0 + tid] = (float)ix;
        atomicAdd(&counts[ix], 1.0f);
    }
    __syncthreads();

    const float* zb = z_e + (size_t)bb * (D * HW) + p0;
    float* ob = out0 + (size_t)bb * (D * HW) + p0;

    for (int i = tid; i < 64 * D; i += 256) {
        int d = i >> 6, r = i & 63;
        float z = zb[(size_t)d * HW + r];
        float c = cb[(size_t)idxS[r] * D + d];
        ob[(size_t)d * HW + r] = z + (c - z);
    }
    for (int i = tid; i < 64 * D; i += 256) {
        int r = i >> 7, d = i & 127;
        atomicAdd(&dw[(size_t)idxS[r] * D + d], zb[(size_t)d * HW + r]);
    }
}

__global__ __launch_bounds__(256) void k_final(const float* __restrict__ ema_count,
                                               const float* __restrict__ ema_weight,
                                               float* __restrict__ out2,
                                               float* __restrict__ out3,
                                               float* __restrict__ out4) {
    int gid = blockIdx.x * 256 + threadIdx.x;   // over K*D
    int k = gid >> 7, d = gid & 127;
    float cnt_raw = out3[k];
    float dw_raw = out4[gid];
    __syncthreads();
    float nc = 0.99f * ema_count[k] + 0.01f * cnt_raw;
    float nw = 0.99f * ema_weight[gid] + 0.01f * dw_raw;
    out4[gid] = nw;
    out2[gid] = nw / fmaxf(nc, 1.0f);
    if (d == 0) out3[k] = nc;
}

extern "C" void kernel_launch(void* const* d_in, const int* in_sizes, int n_in,
                              void* d_out, int out_size, void* d_ws, size_t ws_size,
                              hipStream_t stream) {
    const float* z_e        = (const float*)d_in[0];
    const float* cb         = (const float*)d_in[1];
    const float* ema_count  = (const float*)d_in[2];
    const float* ema_weight = (const float*)d_in[3];
    float* out = (float*)d_out;

    float* cnorm = (float*)d_ws;                                   // K floats
    u64* packed = (u64*)((char*)d_ws + K * 4);                     // NROWS u64

    // fp16-split scratch lives in out regions rewritten later:
    // out0 (8 MB) hosts Ah|Al, out2 (4 MB) hosts the unit-interleaved B.
    u16* Ahg = (u16*)(out + OUT0);
    u16* Alg = Ahg + (size_t)NROWS * D;
    u16* Bg  = (u16*)(out + OUT2);                                 // 256 units x 16 KiB

    k_prep       <<<1536,          256, 0, stream>>>(cb, z_e, Bg, cnorm, Ahg, Alg,
                                                     packed, out + OUT3, out + OUT4);
    k_argmin_mfma<<<1024,          256, 0, stream>>>(Ahg, Alg, Bg, cnorm, packed);
    k_epilogue   <<<NROWS / 64,    256, 0, stream>>>(z_e, cb, packed,
                                                     out + OUT0, out + OUT1,
                                                     out + OUT3, out + OUT4);
    k_final      <<<(K * D) / 256, 256, 0, stream>>>(ema_count, ema_weight,
                                                     out + OUT2, out + OUT3, out + OUT4);
}

// Round 7
// 211.887 us; speedup vs baseline: 1.0292x; 1.0292x over previous
//
#include <hip/hip_runtime.h>

// Problem constants (B=16, D=128, H=32, W=32, K=8192)
#define D 128
#define HW 1024
#define NROWS 16384
#define K 8192
#define NU 32   // 32-col units per block (1024-col k-split / 32)

// d_out layout (float offsets): z_q_st | indices | new_codebook | new_count | new_weight
#define OUT0 0
#define OUT1 2097152
#define OUT2 2113536
#define OUT3 3162112
#define OUT4 3170304

typedef __attribute__((ext_vector_type(8))) _Float16 half8;
typedef __attribute__((ext_vector_type(16))) float f32x16;
typedef unsigned short u16;
typedef unsigned long long u64;

// ---- async global->LDS, 16B per lane (dst = wave-uniform base + lane*16) ----
__device__ __forceinline__ void gld16(const u16* gsrc, u16* ldst) {
    __builtin_amdgcn_global_load_lds(
        (const __attribute__((address_space(1))) unsigned int*)gsrc,
        (__attribute__((address_space(3))) unsigned int*)ldst,
        16, 0, 0);
}

// ---- fused prep: blocks [0,512) codebook-split + cnorm + dw-zero;
//      blocks [512,1536) z-split + packed-init + counts-zero ----
// B layout: [unit g(256)][ Bh: [kk(16)][col(32)][j(8)] | Bl: same ] (16 KiB/unit)
// A layout: [band(n>>5)][ks(8)][lh(2)][row(32)][j(8)]
__global__ __launch_bounds__(256) void k_prep(const float* __restrict__ cb,
                                              const float* __restrict__ z_e,
                                              u16* __restrict__ Bg,
                                              float* __restrict__ cnorm,
                                              u16* __restrict__ Ah, u16* __restrict__ Al,
                                              u64* __restrict__ packed,
                                              float* __restrict__ counts,
                                              float* __restrict__ dw) {
    const int tid = threadIdx.x;
    if (blockIdx.x < 512) {
        int kk = tid & 15;
        int k = blockIdx.x * 16 + (tid >> 4);
        const float* src = cb + (size_t)k * D + kk * 8;
        half8 h, l;
        float s = 0.f;
#pragma unroll
        for (int j = 0; j < 8; ++j) {
            float v = src[j];
            s += v * v;
            _Float16 hv = (_Float16)v;              // RN f32->f16
            _Float16 lv = (_Float16)(v - (float)hv);
            h[j] = hv;
            l[j] = lv;
        }
        int g = k >> 5, col = k & 31;
        size_t offH = (size_t)g * 8192 + ((size_t)kk * 32 + col) * 8;
        *(half8*)((_Float16*)Bg + offH) = h;
        *(half8*)((_Float16*)Bg + offH + 4096) = l;
#pragma unroll
        for (int off = 8; off > 0; off >>= 1) s += __shfl_down(s, off);
        if (kk == 0) cnorm[k] = s;
        // zero dw: 131072 threads x 8 floats = K*D exactly
        float4 z4 = {0.f, 0.f, 0.f, 0.f};
        size_t zi = ((size_t)blockIdx.x * 256 + tid) * 8;
        *(float4*)(dw + zi) = z4;
        *(float4*)(dw + zi + 4) = z4;
    } else {
        int gid = (blockIdx.x - 512) * 256 + tid;   // NROWS*16 threads
        int n  = gid & (NROWS - 1);                 // lane-contiguous n -> coalesced
        int kk = gid >> 14;                         // 0..15
        int b = n >> 10, hw = n & 1023;
        const float* src = z_e + ((size_t)b * D + kk * 8) * HW + hw;
        half8 h, l;
#pragma unroll
        for (int j = 0; j < 8; ++j) {
            float v = src[(size_t)j * HW];
            _Float16 hv = (_Float16)v;
            _Float16 lv = (_Float16)(v - (float)hv);
            h[j] = hv;
            l[j] = lv;
        }
        int rg = n >> 7, band = (n >> 5) & 3, row = n & 31;
        size_t off = (((((size_t)rg * 4 + band) * 8 + (kk >> 1)) * 2 + (kk & 1)) * 32 + row) * 8;
        *(half8*)(Ah + off) = h;
        *(half8*)(Al + off) = l;
        if (kk == 0) {
            packed[n] = ~0ull;                      // +inf sentinel
            if (n < K) counts[n] = 0.f;
        }
    }
}

// ---- main: 3-pass fp16-split distance GEMM + fused argmin, fold ping-pong ----
// R7: six variants all sat at MfmaUtil 37-43% -- the invariant is that each
// unit's fold is data-dependent on the LAST MFMA of that unit's 24-long acc
// chain, so every wave alternates [MFMA chain] -> [chain drain] -> [fold VALU]
// serially. T15 fix: two static accs (accA/accB), 2x-unrolled unit loop; while
// unit u+1 accumulates into one acc, unit u's completed acc is folded, with the
// fold STATICALLY interleaved into the pass-2/3 MFMA sequence (in-order waves
// can't interleave dynamically -- R6 showed the compiler re-sinks hoists).
// Geometry: 256 thr (4 waves x one 32-row tile), 2x16KiB dbuf (parity static),
// 1024 blocks = 128 rg x 8 ks (R5's bijective low-FETCH swizzle),
// launch_bounds(256,3) -> ~160 regs, 3 blocks/CU. Counted vmcnt(5)/body.
__global__ __launch_bounds__(256, 3) void k_argmin_mfma(
        const u16* __restrict__ Ahg, const u16* __restrict__ Alg,
        const u16* __restrict__ Bg,
        const float* __restrict__ cnorm, u64* __restrict__ packed) {
    __shared__ u16 lds[2][8192];                // 2 x 16 KiB

    const int tid = threadIdx.x;
    const int ln  = tid & 63;
    const int l31 = ln & 31;
    const int lh  = ln >> 5;                    // k-half select within frag
    const int wy  = tid >> 6;                   // wave 0..3

    const int bid = blockIdx.x;                 // 1024 = 128 rg x 8 ks
    const int ks_ = (bid >> 3) & 7;             // R5-style bijective swizzle
    const int rg  = (bid & 7) * 16 + (bid >> 6);

    const int k0 = ks_ * 1024;                  // k split
    const int g0 = k0 >> 5;                     // first 32-col B-unit
    const int band = rg * 4 + wy;               // global 32-row band 0..511

    // ---- A fragments -> registers (read once from global; 64 VGPRs) ----
    half8 Ah[8], Al[8];
#pragma unroll
    for (int ks = 0; ks < 8; ++ks) {
        size_t off = ((((size_t)band * 8 + ks) * 2 + lh) * 32 + l31) * 8;
        Ah[ks] = *(const half8*)((const _Float16*)Ahg + off);
        Al[ks] = *(const half8*)((const _Float16*)Alg + off);
    }

    // ---- prologue: stage unit 0 -> lds[0]; full drain (order-robust) ----
    {
        const u16* src = Bg + (size_t)g0 * 8192;
#pragma unroll
        for (int r = 0; r < 4; ++r)
            gld16(src + ((size_t)r * 256 + tid) * 8, lds[0] + (r * 256 + tid) * 8);
    }
    asm volatile("s_waitcnt vmcnt(0)" ::: "memory");
    asm volatile("s_barrier" ::: "memory");

    float minv[16];
    int   mini[16];
#pragma unroll
    for (int r = 0; r < 16; ++r) { minv[r] = INFINITY; mini[r] = 0; }

    f32x16 accA = {}, accB = {};
    float cnA = INFINITY, cnB = INFINITY;       // cnB=INF: first fold is a no-op
    int   cA = 0, cB = 0;

#pragma unroll 1
    for (int u = 0; u < NU; u += 2) {
        // ======== body 1: unit u (lds[0]) -> accA; stage u+1 -> lds[1];
        //          fold prev (accB, cnB, cB) interleaved into pass 2/3 ========
        {
            cA = k0 + u * 32 + l31;
            float cn_new = cnorm[cA];                       // VMEM op 1
            const u16* src = Bg + (size_t)(g0 + u + 1) * 8192;
#pragma unroll
            for (int r = 0; r < 4; ++r)                     // VMEM ops 2..5
                gld16(src + ((size_t)r * 256 + tid) * 8, lds[1] + (r * 256 + tid) * 8);
            // 5 newest (this body's) may stay in flight; stage of unit u retired
            asm volatile("s_waitcnt vmcnt(5)" ::: "memory");
            asm volatile("s_barrier" ::: "memory");

            const _Float16* bh = (const _Float16*)lds[0];
            const _Float16* bl = bh + 4096;

            accA = f32x16{};
            __builtin_amdgcn_s_setprio(1);
#pragma unroll
            for (int ks = 0; ks < 8; ++ks) {                // pass 1: Ah x Bl
                half8 b = *(const half8*)(bl + ((ks * 2 + lh) * 32 + l31) * 8);
                accA = __builtin_amdgcn_mfma_f32_32x32x16_f16(Ah[ks], b, accA, 0, 0, 0);
            }
#pragma unroll
            for (int ks = 0; ks < 8; ++ks) {                // pass 2+3 + fold(prev)
                half8 b = *(const half8*)(bh + ((ks * 2 + lh) * 32 + l31) * 8);
                accA = __builtin_amdgcn_mfma_f32_32x32x16_f16(Ah[ks], b, accA, 0, 0, 0);
                accA = __builtin_amdgcn_mfma_f32_32x32x16_f16(Al[ks], b, accA, 0, 0, 0);
                const int r0 = ks * 2, r1 = r0 + 1;
                float d0 = fmaf(-2.0f, accB[r0], cnB);
                float d1 = fmaf(-2.0f, accB[r1], cnB);
                bool p0 = d0 < minv[r0];
                bool p1 = d1 < minv[r1];
                minv[r0] = p0 ? d0 : minv[r0];  mini[r0] = p0 ? cB : mini[r0];
                minv[r1] = p1 ? d1 : minv[r1];  mini[r1] = p1 ? cB : mini[r1];
            }
            __builtin_amdgcn_s_setprio(0);
            cnA = cn_new;
            // all waves done reading lds[0] before body2 stages u+2 into it
            asm volatile("s_barrier" ::: "memory");
        }

        // ======== body 2: unit u+1 (lds[1]) -> accB; stage u+2 -> lds[0];
        //          fold (accA, cnA, cA) interleaved into pass 2/3 ========
        {
            cB = k0 + (u + 1) * 32 + l31;
            float cn_new = cnorm[cB];                       // VMEM op 1
            if (u + 2 < NU) {
                const u16* src = Bg + (size_t)(g0 + u + 2) * 8192;
#pragma unroll
                for (int r = 0; r < 4; ++r)                 // VMEM ops 2..5
                    gld16(src + ((size_t)r * 256 + tid) * 8, lds[0] + (r * 256 + tid) * 8);
                asm volatile("s_waitcnt vmcnt(5)" ::: "memory");
            } else {
                asm volatile("s_waitcnt vmcnt(0)" ::: "memory");  // tail drain
            }
            asm volatile("s_barrier" ::: "memory");

            const _Float16* bh = (const _Float16*)lds[1];
            const _Float16* bl = bh + 4096;

            accB = f32x16{};
            __builtin_amdgcn_s_setprio(1);
#pragma unroll
            for (int ks = 0; ks < 8; ++ks) {                // pass 1: Ah x Bl
                half8 b = *(const half8*)(bl + ((ks * 2 + lh) * 32 + l31) * 8);
                accB = __builtin_amdgcn_mfma_f32_32x32x16_f16(Ah[ks], b, accB, 0, 0, 0);
            }
#pragma unroll
            for (int ks = 0; ks < 8; ++ks) {                // pass 2+3 + fold(prev)
                half8 b = *(const half8*)(bh + ((ks * 2 + lh) * 32 + l31) * 8);
                accB = __builtin_amdgcn_mfma_f32_32x32x16_f16(Ah[ks], b, accB, 0, 0, 0);
                accB = __builtin_amdgcn_mfma_f32_32x32x16_f16(Al[ks], b, accB, 0, 0, 0);
                const int r0 = ks * 2, r1 = r0 + 1;
                float d0 = fmaf(-2.0f, accA[r0], cnA);
                float d1 = fmaf(-2.0f, accA[r1], cnA);
                bool p0 = d0 < minv[r0];
                bool p1 = d1 < minv[r1];
                minv[r0] = p0 ? d0 : minv[r0];  mini[r0] = p0 ? cA : mini[r0];
                minv[r1] = p1 ? d1 : minv[r1];  mini[r1] = p1 ? cA : mini[r1];
            }
            __builtin_amdgcn_s_setprio(0);
            cnB = cn_new;
            // all waves done reading lds[1] before next body1 stages into it
            asm volatile("s_barrier" ::: "memory");
        }
    }

    // ---- epilogue fold: unit NU-1 (accB) ----
#pragma unroll
    for (int r = 0; r < 16; ++r) {
        float d0 = fmaf(-2.0f, accB[r], cnB);
        bool p = d0 < minv[r];
        minv[r] = p ? d0 : minv[r];
        mini[r] = p ? cB : mini[r];
    }

    // ---- reduce across the 32 l31-lanes sharing each output row ----
#pragma unroll
    for (int r = 0; r < 16; ++r) {
        float v = minv[r];
        int ix = mini[r];
#pragma unroll
        for (int off = 1; off < 32; off <<= 1) {
            float v2 = __shfl_xor(v, off);
            int i2 = __shfl_xor(ix, off);
            if (v2 < v || (v2 == v && i2 < ix)) { v = v2; ix = i2; }
        }
        if (l31 == 0) {
            // C/D row map (m74/m101): row = (reg&3) + 8*(reg>>2) + 4*(lane>>5)
            int row = band * 32 + 4 * lh + (r & 3) + 8 * (r >> 2);
            unsigned int uenc = __float_as_uint(v);
            uenc = (uenc & 0x80000000u) ? ~uenc : (uenc | 0x80000000u);  // monotonic
            u64 pk = ((u64)uenc << 13) | (u64)(unsigned)ix;
            atomicMin(&packed[row], pk);
        }
    }
}

// ---- epilogue: indices, z_q_st, counts, dw ----
__global__ __launch_bounds__(256) void k_epilogue(const float* __restrict__ z_e,
                                                  const float* __restrict__ cb,
                                                  const u64* __restrict__ packed,
                                                  float* __restrict__ out0,
                                                  float* __restrict__ out1,
                                                  float* __restrict__ counts,
                                                  float* __restrict__ dw) {
    __shared__ int idxS[64];
    const int tid = threadIdx.x;
    const int n0 = blockIdx.x * 64;
    const int bb = n0 >> 10, p0 = n0 & 1023;

    if (tid < 64) {
        int ix = (int)(packed[n0 + tid] & 0x1FFFull);
        idxS[tid] = ix;
        out1[n0 + tid] = (float)ix;
        atomicAdd(&counts[ix], 1.0f);
    }
    __syncthreads();

    const float* zb = z_e + (size_t)bb * (D * HW) + p0;
    float* ob = out0 + (size_t)bb * (D * HW) + p0;

    for (int i = tid; i < 64 * D; i += 256) {
        int d = i >> 6, r = i & 63;
        float z = zb[(size_t)d * HW + r];
        float c = cb[(size_t)idxS[r] * D + d];
        ob[(size_t)d * HW + r] = z + (c - z);
    }
    for (int i = tid; i < 64 * D; i += 256) {
        int r = i >> 7, d = i & 127;
        atomicAdd(&dw[(size_t)idxS[r] * D + d], zb[(size_t)d * HW + r]);
    }
}

__global__ __launch_bounds__(256) void k_final(const float* __restrict__ ema_count,
                                               const float* __restrict__ ema_weight,
                                               float* __restrict__ out2,
                                               float* __restrict__ out3,
                                               float* __restrict__ out4) {
    int gid = blockIdx.x * 256 + threadIdx.x;   // over K*D
    int k = gid >> 7, d = gid & 127;
    float cnt_raw = out3[k];
    float dw_raw = out4[gid];
    __syncthreads();
    float nc = 0.99f * ema_count[k] + 0.01f * cnt_raw;
    float nw = 0.99f * ema_weight[gid] + 0.01f * dw_raw;
    out4[gid] = nw;
    out2[gid] = nw / fmaxf(nc, 1.0f);
    if (d == 0) out3[k] = nc;
}

extern "C" void kernel_launch(void* const* d_in, const int* in_sizes, int n_in,
                              void* d_out, int out_size, void* d_ws, size_t ws_size,
                              hipStream_t stream) {
    const float* z_e        = (const float*)d_in[0];
    const float* cb         = (const float*)d_in[1];
    const float* ema_count  = (const float*)d_in[2];
    const float* ema_weight = (const float*)d_in[3];
    float* out = (float*)d_out;

    float* cnorm = (float*)d_ws;                                   // K floats
    u64* packed = (u64*)((char*)d_ws + K * 4);                     // NROWS u64

    // fp16-split scratch lives in out regions rewritten later:
    // out0 (8 MB) hosts Ah|Al, out2 (4 MB) hosts the unit-interleaved B.
    u16* Ahg = (u16*)(out + OUT0);
    u16* Alg = Ahg + (size_t)NROWS * D;
    u16* Bg  = (u16*)(out + OUT2);                                 // 256 units x 16 KiB

    k_prep       <<<1536,          256, 0, stream>>>(cb, z_e, Bg, cnorm, Ahg, Alg,
                                                     packed, out + OUT3, out + OUT4);
    k_argmin_mfma<<<1024,          256, 0, stream>>>(Ahg, Alg, Bg, cnorm, packed);
    k_epilogue   <<<NROWS / 64,    256, 0, stream>>>(z_e, cb, packed,
                                                     out + OUT0, out + OUT1,
                                                     out + OUT3, out + OUT4);
    k_final      <<<(K * D) / 256, 256, 0, stream>>>(ema_count, ema_weight,
                                                     out + OUT2, out + OUT3, out + OUT4);
}

// Round 8
// 200.574 us; speedup vs baseline: 1.0872x; 1.0564x over previous
//
#include <hip/hip_runtime.h>

// Problem constants (B=16, D=128, H=32, W=32, K=8192)
#define D 128
#define HW 1024
#define NROWS 16384
#define K 8192
#define NU 32   // 64-col units per block (2048-col k-split / 64)

// d_out layout (float offsets): z_q_st | indices | new_codebook | new_count | new_weight
#define OUT0 0
#define OUT1 2097152
#define OUT2 2113536
#define OUT3 3162112
#define OUT4 3170304

typedef __attribute__((ext_vector_type(8))) _Float16 half8;
typedef __attribute__((ext_vector_type(16))) float f32x16;
typedef unsigned short u16;
typedef unsigned long long u64;

// ---- async global->LDS, 16B per lane (dst = wave-uniform base + lane*16) ----
__device__ __forceinline__ void gld16(const u16* gsrc, u16* ldst) {
    __builtin_amdgcn_global_load_lds(
        (const __attribute__((address_space(1))) unsigned int*)gsrc,
        (__attribute__((address_space(3))) unsigned int*)ldst,
        16, 0, 0);
}

// ---- prep: 512 blocks, codebook-split + cnorm + dw-zero + packed/counts init ----
// (z-side conversion moved INTO k_argmin_mfma -- saves a 48 MB pass; R8)
// B layout: [unit g(128)][ Bh: [kk(16)][col(64)][j(8)] | Bl: same ] (32 KiB/unit)
__global__ __launch_bounds__(256) void k_prep(const float* __restrict__ cb,
                                              u16* __restrict__ Bg,
                                              float* __restrict__ cnorm,
                                              u64* __restrict__ packed,
                                              float* __restrict__ counts,
                                              float* __restrict__ dw) {
    const int tid = threadIdx.x;
    int kk = tid & 15;
    int k = blockIdx.x * 16 + (tid >> 4);
    const float* src = cb + (size_t)k * D + kk * 8;
    half8 h, l;
    float s = 0.f;
#pragma unroll
    for (int j = 0; j < 8; ++j) {
        float v = src[j];
        s += v * v;
        _Float16 hv = (_Float16)v;              // RN f32->f16
        _Float16 lv = (_Float16)(v - (float)hv);
        h[j] = hv;
        l[j] = lv;
    }
    int g = k >> 6, col = k & 63;
    size_t offH = (size_t)g * 16384 + ((size_t)kk * 64 + col) * 8;
    *(half8*)((_Float16*)Bg + offH) = h;
    *(half8*)((_Float16*)Bg + offH + 8192) = l;
#pragma unroll
    for (int off = 8; off > 0; off >>= 1) s += __shfl_down(s, off);
    if (kk == 0) cnorm[k] = s;
    // zero dw: 131072 threads x 8 floats = K*D exactly
    float4 z4 = {0.f, 0.f, 0.f, 0.f};
    size_t zi = ((size_t)blockIdx.x * 256 + tid) * 8;
    *(float4*)(dw + zi) = z4;
    *(float4*)(dw + zi + 4) = z4;
    // packed sentinel + counts zero (131072 threads cover NROWS and K)
    int gid = blockIdx.x * 256 + tid;
    if (gid < NROWS) packed[gid] = ~0ull;       // +inf sentinel
    if (gid < K) counts[gid] = 0.f;
}

// ---- main: 3-pass fp16-split distance GEMM + fused argmin (R0 structure) ----
// grid: 128 rowgroups x 4 ksplits, 512 threads (8 waves: wy 0..3 x wx 0..1).
// Wave tile: 32 rows x 32 cols; A-frags pinned in VGPRs (converted IN-KERNEL
// from z_e f32 -- R8 fusion, bit-identical split math to the old prep pass);
// B in 64-col units, 2x32 KiB LDS dbuf (-> 2 blocks/CU, 4 waves/SIMD) with
// in-flight prefetch across raw s_barrier via explicit vmcnt(4).
__global__ __launch_bounds__(512, 4) void k_argmin_mfma(
        const float* __restrict__ z_e,
        const u16* __restrict__ Bg,
        const float* __restrict__ cnorm, u64* __restrict__ packed) {
    __shared__ u16 lds[2][16384];               // 2 x 32 KiB

    const int tid = threadIdx.x;
    const int ln  = tid & 63;
    const int l31 = ln & 31;
    const int lh  = ln >> 5;                    // k-half select within frag
    const int wv  = tid >> 6;                   // 0..7
    const int wy  = wv & 3;                     // row band 0..3
    const int wx  = wv >> 2;                    // col half 0..1

    const int rg = blockIdx.x >> 2;             // 128 row groups x 128 rows
    const int k0 = (blockIdx.x & 3) * 2048;     // k split
    const int g0 = k0 >> 6;                     // first 64-col B-unit

    // ---- A fragments: read this lane's row from z_e (f32, coalesced across
    // lanes: 32 consecutive hw per d) and fp16-split in-register. Same RN
    // split as the old k_prep z-pass -> bit-identical fragments. Once per
    // block; amortized over the 32-unit K loop. 64 VGPRs resident. ----
    const int row = (rg * 4 + wy) * 32 + l31;   // 32 rows/band, one b per band
    const float* zrow = z_e + ((size_t)(row >> 10)) * (D * HW) + (row & 1023);
    half8 Ah[8], Al[8];
#pragma unroll
    for (int ks = 0; ks < 8; ++ks) {
        half8 h, l;
#pragma unroll
        for (int j = 0; j < 8; ++j) {
            float v = zrow[(size_t)(ks * 16 + lh * 8 + j) * HW];
            _Float16 hv = (_Float16)v;          // RN f32->f16
            h[j] = hv;
            l[j] = (_Float16)(v - (float)hv);
        }
        Ah[ks] = h;
        Al[ks] = l;
    }

    // ---- prologue: stage unit 0 (32 KiB, 4 gld16/thread) ----
    {
        const u16* src = Bg + (size_t)g0 * 16384;
#pragma unroll
        for (int r = 0; r < 4; ++r)
            gld16(src + ((size_t)r * 512 + tid) * 8, lds[0] + (r * 512 + tid) * 8);
    }

    float minv[16];
    int   mini[16];
#pragma unroll
    for (int r = 0; r < 16; ++r) { minv[r] = INFINITY; mini[r] = 0; }

#pragma unroll 1
    for (int u = 0; u < NU; ++u) {
        const u16* buf = lds[u & 1];
        const int c0 = k0 + u * 64 + wx * 32 + l31;

        // cn load first (older than the prefetch -> completed once vmcnt<=4)
        float cn0 = cnorm[c0];

        if (u + 1 < NU) {
            const u16* src = Bg + (size_t)(g0 + u + 1) * 16384;
            u16* dst = lds[(u + 1) & 1];
#pragma unroll
            for (int r = 0; r < 4; ++r)
                gld16(src + ((size_t)r * 512 + tid) * 8, dst + (r * 512 + tid) * 8);
            // wait for *this* unit's stage; next unit's 4 loads stay in flight
            asm volatile("s_waitcnt vmcnt(4)" ::: "memory");
        } else {
            asm volatile("s_waitcnt vmcnt(0)" ::: "memory");
        }
        asm volatile("s_barrier" ::: "memory");

        f32x16 acc = {};
        const _Float16* bh = (const _Float16*)buf;
        const _Float16* bl = bh + 8192;

        // pass 1: Ah x Bl
#pragma unroll
        for (int ks = 0; ks < 8; ++ks) {
            const int bo = ((ks * 2 + lh) * 64 + wx * 32 + l31) * 8;
            half8 b0 = *(const half8*)(bl + bo);
            acc = __builtin_amdgcn_mfma_f32_32x32x16_f16(Ah[ks], b0, acc, 0, 0, 0);
        }
        // passes 2+3: Ah x Bh, Al x Bh (B-frag shared)
#pragma unroll
        for (int ks = 0; ks < 8; ++ks) {
            const int bo = ((ks * 2 + lh) * 64 + wx * 32 + l31) * 8;
            half8 b0 = *(const half8*)(bh + bo);
            acc = __builtin_amdgcn_mfma_f32_32x32x16_f16(Ah[ks], b0, acc, 0, 0, 0);
            acc = __builtin_amdgcn_mfma_f32_32x32x16_f16(Al[ks], b0, acc, 0, 0, 0);
        }

        // fold dist = cnorm - 2*dot into running argmin
#pragma unroll
        for (int r = 0; r < 16; ++r) {
            float d0 = fmaf(-2.0f, acc[r], cn0);
            if (d0 < minv[r]) { minv[r] = d0; mini[r] = c0; }
        }
        // all waves done reading buf before its sibling is overwritten next iter
        asm volatile("s_barrier" ::: "memory");
    }

    // ---- reduce across the 32 l31-lanes sharing each output row ----
#pragma unroll
    for (int r = 0; r < 16; ++r) {
        float v = minv[r];
        int ix = mini[r];
#pragma unroll
        for (int off = 1; off < 32; off <<= 1) {
            float v2 = __shfl_xor(v, off);
            int i2 = __shfl_xor(ix, off);
            if (v2 < v || (v2 == v && i2 < ix)) { v = v2; ix = i2; }
        }
        if (l31 == 0) {
            // C/D row map (m74/m101): row = (reg&3) + 8*(reg>>2) + 4*(lane>>5)
            int orow = rg * 128 + wy * 32 + 4 * lh + (r & 3) + 8 * (r >> 2);
            unsigned int uenc = __float_as_uint(v);
            uenc = (uenc & 0x80000000u) ? ~uenc : (uenc | 0x80000000u);  // monotonic
            u64 pk = ((u64)uenc << 13) | (u64)(unsigned)ix;
            atomicMin(&packed[orow], pk);
        }
    }
}

// ---- epilogue: indices, z_q_st, counts, dw (z staged in LDS once -- R8) ----
__global__ __launch_bounds__(256) void k_epilogue(const float* __restrict__ z_e,
                                                  const float* __restrict__ cb,
                                                  const u64* __restrict__ packed,
                                                  float* __restrict__ out0,
                                                  float* __restrict__ out1,
                                                  float* __restrict__ counts,
                                                  float* __restrict__ dw) {
    __shared__ float zS[128][65];               // +1 pad: conflict-free both orders
    __shared__ int idxS[64];
    const int tid = threadIdx.x;
    const int n0 = blockIdx.x * 64;
    const int bb = n0 >> 10, p0 = n0 & 1023;

    if (tid < 64) {
        int ix = (int)(packed[n0 + tid] & 0x1FFFull);
        idxS[tid] = ix;
        out1[n0 + tid] = (float)ix;
        atomicAdd(&counts[ix], 1.0f);
    }
    __syncthreads();

    const float* zb = z_e + (size_t)bb * (D * HW) + p0;
    float* ob = out0 + (size_t)bb * (D * HW) + p0;

    // pass 1: read z once (coalesced), stage to LDS, write z_q_st
    for (int i = tid; i < 64 * D; i += 256) {
        int d = i >> 6, r = i & 63;
        float z = zb[(size_t)d * HW + r];
        zS[d][r] = z;
        float c = cb[(size_t)idxS[r] * D + d];
        ob[(size_t)d * HW + r] = z + (c - z);
    }
    __syncthreads();
    // pass 2: dw scatter (d-inner -> coalesced per codebook row), z from LDS
    for (int i = tid; i < 64 * D; i += 256) {
        int r = i >> 7, d = i & 127;
        atomicAdd(&dw[(size_t)idxS[r] * D + d], zS[d][r]);
    }
}

__global__ __launch_bounds__(256) void k_final(const float* __restrict__ ema_count,
                                               const float* __restrict__ ema_weight,
                                               float* __restrict__ out2,
                                               float* __restrict__ out3,
                                               float* __restrict__ out4) {
    int gid = blockIdx.x * 256 + threadIdx.x;   // over K*D
    int k = gid >> 7, d = gid & 127;
    float cnt_raw = out3[k];
    float dw_raw = out4[gid];
    __syncthreads();
    float nc = 0.99f * ema_count[k] + 0.01f * cnt_raw;
    float nw = 0.99f * ema_weight[gid] + 0.01f * dw_raw;
    out4[gid] = nw;
    out2[gid] = nw / fmaxf(nc, 1.0f);
    if (d == 0) out3[k] = nc;
}

extern "C" void kernel_launch(void* const* d_in, const int* in_sizes, int n_in,
                              void* d_out, int out_size, void* d_ws, size_t ws_size,
                              hipStream_t stream) {
    const float* z_e        = (const float*)d_in[0];
    const float* cb         = (const float*)d_in[1];
    const float* ema_count  = (const float*)d_in[2];
    const float* ema_weight = (const float*)d_in[3];
    float* out = (float*)d_out;

    float* cnorm = (float*)d_ws;                                   // K floats
    u64* packed = (u64*)((char*)d_ws + K * 4);                     // NROWS u64

    // B-split scratch lives in out2 (4 MB), rewritten later by k_final.
    u16* Bg = (u16*)(out + OUT2);                                  // 128 units x 32 KiB

    k_prep       <<<512,           256, 0, stream>>>(cb, Bg, cnorm,
                                                     packed, out + OUT3, out + OUT4);
    k_argmin_mfma<<<512,           512, 0, stream>>>(z_e, Bg, cnorm, packed);
    k_epilogue   <<<NROWS / 64,    256, 0, stream>>>(z_e, cb, packed,
                                                     out + OUT0, out + OUT1,
                                                     out + OUT3, out + OUT4);
    k_final      <<<(K * D) / 256, 256, 0, stream>>>(ema_count, ema_weight,
                                                     out + OUT2, out + OUT3, out + OUT4);
}

// Round 9
// 197.585 us; speedup vs baseline: 1.1037x; 1.0151x over previous
//
#include <hip/hip_runtime.h>

// Problem constants (B=16, D=128, H=32, W=32, K=8192)
#define D 128
#define HW 1024
#define NROWS 16384
#define K 8192
#define NU 32   // 64-col units per block (2048-col k-split / 64)

// d_out layout (float offsets): z_q_st | indices | new_codebook | new_count | new_weight
#define OUT0 0
#define OUT1 2097152
#define OUT2 2113536
#define OUT3 3162112
#define OUT4 3170304

typedef __attribute__((ext_vector_type(8))) _Float16 half8;
typedef __attribute__((ext_vector_type(16))) float f32x16;
typedef unsigned short u16;
typedef unsigned long long u64;

// ---- async global->LDS, 16B per lane (dst = wave-uniform base + lane*16) ----
__device__ __forceinline__ void gld16(const u16* gsrc, u16* ldst) {
    __builtin_amdgcn_global_load_lds(
        (const __attribute__((address_space(1))) unsigned int*)gsrc,
        (__attribute__((address_space(3))) unsigned int*)ldst,
        16, 0, 0);
}

// ---- prep: 512 blocks, codebook-split + cnorm + dw-zero + packed/counts init ----
// B layout: [unit g(128)][ Bh: [kk(16)][col(64)][j(8)] | Bl: same ] (32 KiB/unit)
__global__ __launch_bounds__(256) void k_prep(const float* __restrict__ cb,
                                              u16* __restrict__ Bg,
                                              float* __restrict__ cnorm,
                                              u64* __restrict__ packed,
                                              float* __restrict__ counts,
                                              float* __restrict__ dw) {
    const int tid = threadIdx.x;
    int kk = tid & 15;
    int k = blockIdx.x * 16 + (tid >> 4);
    const float* src = cb + (size_t)k * D + kk * 8;
    half8 h, l;
    float s = 0.f;
#pragma unroll
    for (int j = 0; j < 8; ++j) {
        float v = src[j];
        s += v * v;
        _Float16 hv = (_Float16)v;              // RN f32->f16
        _Float16 lv = (_Float16)(v - (float)hv);
        h[j] = hv;
        l[j] = lv;
    }
    int g = k >> 6, col = k & 63;
    size_t offH = (size_t)g * 16384 + ((size_t)kk * 64 + col) * 8;
    *(half8*)((_Float16*)Bg + offH) = h;
    *(half8*)((_Float16*)Bg + offH + 8192) = l;
#pragma unroll
    for (int off = 8; off > 0; off >>= 1) s += __shfl_down(s, off);
    if (kk == 0) cnorm[k] = s;
    // zero dw: 131072 threads x 8 floats = K*D exactly
    float4 z4 = {0.f, 0.f, 0.f, 0.f};
    size_t zi = ((size_t)blockIdx.x * 256 + tid) * 8;
    *(float4*)(dw + zi) = z4;
    *(float4*)(dw + zi + 4) = z4;
    // packed sentinel + counts zero (131072 threads cover NROWS and K)
    int gid = blockIdx.x * 256 + tid;
    if (gid < NROWS) packed[gid] = ~0ull;       // +inf sentinel
    if (gid < K) counts[gid] = 0.f;
}

// ---- main: 3-pass fp16-split distance GEMM + fused argmin (R0 structure) ----
// grid: 128 rowgroups x 4 ksplits, 512 threads (8 waves: wy 0..3 x wx 0..1).
// Wave tile: 32 rows x 32 cols; A-frags pinned in VGPRs (converted in-kernel
// from z_e f32 -- R8 fusion); B in 64-col units, 2x32 KiB LDS dbuf
// (2 blocks/CU) with in-flight prefetch across raw s_barrier via vmcnt(4).
// VERIFIED at 106.7-107.8 us / MfmaUtil 43-45% -- do not touch (R0-R7 showed
// every schedule/geometry variant lands at 37-43% MfmaUtil; m97-class plateau).
__global__ __launch_bounds__(512, 4) void k_argmin_mfma(
        const float* __restrict__ z_e,
        const u16* __restrict__ Bg,
        const float* __restrict__ cnorm, u64* __restrict__ packed) {
    __shared__ u16 lds[2][16384];               // 2 x 32 KiB

    const int tid = threadIdx.x;
    const int ln  = tid & 63;
    const int l31 = ln & 31;
    const int lh  = ln >> 5;                    // k-half select within frag
    const int wv  = tid >> 6;                   // 0..7
    const int wy  = wv & 3;                     // row band 0..3
    const int wx  = wv >> 2;                    // col half 0..1

    const int rg = blockIdx.x >> 2;             // 128 row groups x 128 rows
    const int k0 = (blockIdx.x & 3) * 2048;     // k split
    const int g0 = k0 >> 6;                     // first 64-col B-unit

    // ---- A fragments: read this lane's row from z_e (f32, coalesced across
    // lanes) and fp16-split in-register; bit-identical to the old prep pass ----
    const int row = (rg * 4 + wy) * 32 + l31;
    const float* zrow = z_e + ((size_t)(row >> 10)) * (D * HW) + (row & 1023);
    half8 Ah[8], Al[8];
#pragma unroll
    for (int ks = 0; ks < 8; ++ks) {
        half8 h, l;
#pragma unroll
        for (int j = 0; j < 8; ++j) {
            float v = zrow[(size_t)(ks * 16 + lh * 8 + j) * HW];
            _Float16 hv = (_Float16)v;          // RN f32->f16
            h[j] = hv;
            l[j] = (_Float16)(v - (float)hv);
        }
        Ah[ks] = h;
        Al[ks] = l;
    }

    // ---- prologue: stage unit 0 (32 KiB, 4 gld16/thread) ----
    {
        const u16* src = Bg + (size_t)g0 * 16384;
#pragma unroll
        for (int r = 0; r < 4; ++r)
            gld16(src + ((size_t)r * 512 + tid) * 8, lds[0] + (r * 512 + tid) * 8);
    }

    float minv[16];
    int   mini[16];
#pragma unroll
    for (int r = 0; r < 16; ++r) { minv[r] = INFINITY; mini[r] = 0; }

#pragma unroll 1
    for (int u = 0; u < NU; ++u) {
        const u16* buf = lds[u & 1];
        const int c0 = k0 + u * 64 + wx * 32 + l31;

        // cn load first (older than the prefetch -> completed once vmcnt<=4)
        float cn0 = cnorm[c0];

        if (u + 1 < NU) {
            const u16* src = Bg + (size_t)(g0 + u + 1) * 16384;
            u16* dst = lds[(u + 1) & 1];
#pragma unroll
            for (int r = 0; r < 4; ++r)
                gld16(src + ((size_t)r * 512 + tid) * 8, dst + (r * 512 + tid) * 8);
            // wait for *this* unit's stage; next unit's 4 loads stay in flight
            asm volatile("s_waitcnt vmcnt(4)" ::: "memory");
        } else {
            asm volatile("s_waitcnt vmcnt(0)" ::: "memory");
        }
        asm volatile("s_barrier" ::: "memory");

        f32x16 acc = {};
        const _Float16* bh = (const _Float16*)buf;
        const _Float16* bl = bh + 8192;

        // pass 1: Ah x Bl
#pragma unroll
        for (int ks = 0; ks < 8; ++ks) {
            const int bo = ((ks * 2 + lh) * 64 + wx * 32 + l31) * 8;
            half8 b0 = *(const half8*)(bl + bo);
            acc = __builtin_amdgcn_mfma_f32_32x32x16_f16(Ah[ks], b0, acc, 0, 0, 0);
        }
        // passes 2+3: Ah x Bh, Al x Bh (B-frag shared)
#pragma unroll
        for (int ks = 0; ks < 8; ++ks) {
            const int bo = ((ks * 2 + lh) * 64 + wx * 32 + l31) * 8;
            half8 b0 = *(const half8*)(bh + bo);
            acc = __builtin_amdgcn_mfma_f32_32x32x16_f16(Ah[ks], b0, acc, 0, 0, 0);
            acc = __builtin_amdgcn_mfma_f32_32x32x16_f16(Al[ks], b0, acc, 0, 0, 0);
        }

        // fold dist = cnorm - 2*dot into running argmin
#pragma unroll
        for (int r = 0; r < 16; ++r) {
            float d0 = fmaf(-2.0f, acc[r], cn0);
            if (d0 < minv[r]) { minv[r] = d0; mini[r] = c0; }
        }
        // all waves done reading buf before its sibling is overwritten next iter
        asm volatile("s_barrier" ::: "memory");
    }

    // ---- reduce across the 32 l31-lanes sharing each output row ----
#pragma unroll
    for (int r = 0; r < 16; ++r) {
        float v = minv[r];
        int ix = mini[r];
#pragma unroll
        for (int off = 1; off < 32; off <<= 1) {
            float v2 = __shfl_xor(v, off);
            int i2 = __shfl_xor(ix, off);
            if (v2 < v || (v2 == v && i2 < ix)) { v = v2; ix = i2; }
        }
        if (l31 == 0) {
            // C/D row map (m74/m101): row = (reg&3) + 8*(reg>>2) + 4*(lane>>5)
            int orow = rg * 128 + wy * 32 + 4 * lh + (r & 3) + 8 * (r >> 2);
            unsigned int uenc = __float_as_uint(v);
            uenc = (uenc & 0x80000000u) ? ~uenc : (uenc | 0x80000000u);  // monotonic
            u64 pk = ((u64)uenc << 13) | (u64)(unsigned)ix;
            atomicMin(&packed[orow], pk);
        }
    }
}

// ---- epilogue: indices, z_q_st, counts, dw ----
// R9: 512 blocks x 32 rows (2 blocks/CU, 8 waves/CU -- was 1 wave/SIMD) and
// the cb gather made COALESCED by staging the block's 32 codebook rows into
// LDS with d-inner waves (was: 64 distinct cachelines per wave-load, 1 wave
// per SIMD to hide them). z transposed through zS; both LDS layouts padded
// odd-stride -> <=2-way bank aliasing (free, m136) on both access orders.
__global__ __launch_bounds__(256) void k_epilogue(const float* __restrict__ z_e,
                                                  const float* __restrict__ cb,
                                                  const u64* __restrict__ packed,
                                                  float* __restrict__ out0,
                                                  float* __restrict__ out1,
                                                  float* __restrict__ counts,
                                                  float* __restrict__ dw) {
    __shared__ float zS[128][33];               // z transposed; stride 33
    __shared__ float cbS[32][129];              // gathered cb rows; stride 129
    __shared__ int idxS[32];
    const int tid = threadIdx.x;
    const int n0 = blockIdx.x * 32;
    const int bb = n0 >> 10, p0 = n0 & 1023;

    if (tid < 32) {
        int ix = (int)(packed[n0 + tid] & 0x1FFFull);
        idxS[tid] = ix;
        out1[n0 + tid] = (float)ix;
        atomicAdd(&counts[ix], 1.0f);
    }
    __syncthreads();

    const float* zb = z_e + (size_t)bb * (D * HW) + p0;
    float* ob = out0 + (size_t)bb * (D * HW) + p0;

    // stage cb rows (one row per 128-thread group -> 256B coalesced reads)
    for (int i = tid; i < 32 * D; i += 256) {
        int row = i >> 7, d = i & 127;
        cbS[row][d] = cb[(size_t)idxS[row] * D + d];
    }
    // stage z (r-inner -> 128B coalesced reads), transposed into zS
    for (int i = tid; i < 32 * D; i += 256) {
        int d = i >> 5, r = i & 31;
        zS[d][r] = zb[(size_t)d * HW + r];
    }
    __syncthreads();
    // z_q_st: coalesced stores; z from zS, c from cbS (both conflict-free)
    for (int i = tid; i < 32 * D; i += 256) {
        int d = i >> 5, r = i & 31;
        float z = zS[d][r];
        float c = cbS[r][d];
        ob[(size_t)d * HW + r] = z + (c - z);
    }
    // dw scatter: one row per 128-thread group -> 256B coalesced atomics
    for (int i = tid; i < 32 * D; i += 256) {
        int r = i >> 7, d = i & 127;
        atomicAdd(&dw[(size_t)idxS[r] * D + d], zS[d][r]);
    }
}

// ---- final: EMA update, float4-vectorized (R9) ----
__global__ __launch_bounds__(256) void k_final(const float* __restrict__ ema_count,
                                               const float* __restrict__ ema_weight,
                                               float* __restrict__ out2,
                                               float* __restrict__ out3,
                                               float* __restrict__ out4) {
    int gid = blockIdx.x * 256 + threadIdx.x;   // over K*D/4
    int k = gid >> 5, d4 = gid & 31;
    float cnt_raw = out3[k];
    float4 dw4 = *(const float4*)(out4 + (size_t)gid * 4);
    float4 ew4 = *(const float4*)(ema_weight + (size_t)gid * 4);
    float ec = ema_count[k];
    __syncthreads();                            // out3[k] read-before-write (in-block)
    float nc = 0.99f * ec + 0.01f * cnt_raw;
    float den = fmaxf(nc, 1.0f);
    float4 nw, o2;
    nw.x = 0.99f * ew4.x + 0.01f * dw4.x;  o2.x = nw.x / den;
    nw.y = 0.99f * ew4.y + 0.01f * dw4.y;  o2.y = nw.y / den;
    nw.z = 0.99f * ew4.z + 0.01f * dw4.z;  o2.z = nw.z / den;
    nw.w = 0.99f * ew4.w + 0.01f * dw4.w;  o2.w = nw.w / den;
    *(float4*)(out4 + (size_t)gid * 4) = nw;
    *(float4*)(out2 + (size_t)gid * 4) = o2;
    if (d4 == 0) out3[k] = nc;
}

extern "C" void kernel_launch(void* const* d_in, const int* in_sizes, int n_in,
                              void* d_out, int out_size, void* d_ws, size_t ws_size,
                              hipStream_t stream) {
    const float* z_e        = (const float*)d_in[0];
    const float* cb         = (const float*)d_in[1];
    const float* ema_count  = (const float*)d_in[2];
    const float* ema_weight = (const float*)d_in[3];
    float* out = (float*)d_out;

    float* cnorm = (float*)d_ws;                                   // K floats
    u64* packed = (u64*)((char*)d_ws + K * 4);                     // NROWS u64

    // B-split scratch lives in out2 (4 MB), rewritten later by k_final.
    u16* Bg = (u16*)(out + OUT2);                                  // 128 units x 32 KiB

    k_prep       <<<512,               256, 0, stream>>>(cb, Bg, cnorm,
                                                         packed, out + OUT3, out + OUT4);
    k_argmin_mfma<<<512,               512, 0, stream>>>(z_e, Bg, cnorm, packed);
    k_epilogue   <<<NROWS / 32,        256, 0, stream>>>(z_e, cb, packed,
                                                         out + OUT0, out + OUT1,
                                                         out + OUT3, out + OUT4);
    k_final      <<<(K * D / 4) / 256, 256, 0, stream>>>(ema_count, ema_weight,
                                                         out + OUT2, out + OUT3, out + OUT4);
}